// Round 1
// baseline (1583.850 us; speedup 1.0000x reference)
//
#include <hip/hip_runtime.h>
#include <stdint.h>

#define NG   64
#define NTOK 8192
#define KDIM 2560
#define NDIM 1664
#define BM   128
#define BN   128
#define BK   32
#define NKITER (KDIM / BK)   /* 80 */
#define ASTRIDE 40           /* A LDS row stride in bf16: 32 + 8 pad (breaks pow2 bank stride) */

typedef __attribute__((ext_vector_type(8))) short bf16x8;
typedef __attribute__((ext_vector_type(4))) float f32x4;
typedef __attribute__((ext_vector_type(4))) unsigned int u32x4;
typedef __attribute__((ext_vector_type(2))) unsigned int u32x2;

// pack two fp32 -> two bf16 (round-half-up) in one v_perm_b32
static __device__ __forceinline__ unsigned pk2(float a, float b) {
    unsigned ua = __float_as_uint(a) + 0x8000u;
    unsigned ub = __float_as_uint(b) + 0x8000u;
    // result bytes [1:0] = ua bytes [3:2], bytes [3:2] = ub bytes [3:2]
    return __builtin_amdgcn_perm(ub, ua, 0x07060302u);
}

__global__ __launch_bounds__(256, 2)
void grouped_gemm(const float* __restrict__ X, const float* __restrict__ W,
                  const int* __restrict__ counts, float* __restrict__ Y) {
    const int nt = blockIdx.x;   // 0..12  N-tile
    const int mt = blockIdx.y;   // 0..1   M-tile within expert (CAP=256 -> <=2 tiles of 128)
    const int g  = blockIdx.z;   // 0..63  expert

    // prefix-sum of counts -> start of this expert's contiguous token rows
    int start = 0, cnt = 0;
    #pragma unroll 1
    for (int i = 0; i < NG; ++i) {
        int c = counts[i];
        start += (i < g) ? c : 0;
        cnt = (i == g) ? c : cnt;
    }
    const int m0 = mt * BM;
    if (m0 >= cnt) return;                 // empty tile -> exit
    const int nb = nt * BN;

    const int tid  = threadIdx.x;
    const int lane = tid & 63;
    const int wid  = tid >> 6;             // 4 waves, 2x2 over (M,N)
    const int wm   = (wid >> 1) * 64;
    const int wn   = (wid & 1) * 64;

    __shared__ unsigned short Ash[BM * ASTRIDE];   // [m][k] k-fast, stride 40
    __shared__ unsigned short Bsh[BN * BK];        // [n][k] k-fast, 16B-unit XOR swizzle

    // ---- A staging mapping: thread covers 8 k's of 2 rows (r, r+64) ----
    const int ar  = tid >> 2;              // 0..63
    const int akq = (tid & 3) * 8;         // 0,8,16,24
    int gr0 = start + m0 + ar;       if (gr0 > NTOK - 1) gr0 = NTOK - 1;   // clamp: padded rows read
    int gr1 = start + m0 + ar + 64;  if (gr1 > NTOK - 1) gr1 = NTOK - 1;   // junk, never stored
    const float* ap0 = X + (size_t)gr0 * KDIM + akq;
    const float* ap1 = X + (size_t)gr1 * KDIM + akq;

    // ---- B staging mapping: 4x4 register transpose block at (k4, n0) ----
    const int l5  = tid & 31;
    const int bk4 = (tid >> 5) * 4;        // 0..28
    const int bn0 = l5 * 4;                // 0..124
    const float* bp = W + (size_t)g * KDIM * NDIM + (size_t)bk4 * NDIM + nb + bn0;
    // swizzle: 16B unit u (=k/8) stored at u ^ ((n>>2)&3); n0..n0+3 share n>>2 = l5
    const int bw0 = bn0 * BK + ((bk4 >> 3) ^ (l5 & 3)) * 8 + ((bk4 >> 2) & 1) * 4;

    f32x4 acc[4][4];
    #pragma unroll
    for (int i = 0; i < 4; ++i)
        #pragma unroll
        for (int j = 0; j < 4; ++j)
            acc[i][j] = (f32x4)0.0f;

    const int fm = lane & 15;              // fragment col/row index
    const int fq = lane >> 4;              // quad -> k-chunk

    // preload K-tile 0 into registers
    f32x4 a0 = *(const f32x4*)(ap0);        f32x4 a1 = *(const f32x4*)(ap0 + 4);
    f32x4 a2 = *(const f32x4*)(ap1);        f32x4 a3 = *(const f32x4*)(ap1 + 4);
    f32x4 b0 = *(const f32x4*)(bp);
    f32x4 b1 = *(const f32x4*)(bp + NDIM);
    f32x4 b2 = *(const f32x4*)(bp + 2 * NDIM);
    f32x4 b3 = *(const f32x4*)(bp + 3 * NDIM);
    ap0 += BK; ap1 += BK; bp += (size_t)BK * NDIM;

    for (int kt = 0; kt < NKITER; ++kt) {
        __syncthreads();   // previous iter's fragment reads complete before overwrite
        // convert + store staged registers to LDS
        u32x4 pa0 = { pk2(a0[0],a0[1]), pk2(a0[2],a0[3]), pk2(a1[0],a1[1]), pk2(a1[2],a1[3]) };
        u32x4 pa1 = { pk2(a2[0],a2[1]), pk2(a2[2],a2[3]), pk2(a3[0],a3[1]), pk2(a3[2],a3[3]) };
        *(u32x4*)&Ash[ar * ASTRIDE + akq]        = pa0;
        *(u32x4*)&Ash[(ar + 64) * ASTRIDE + akq] = pa1;
        #pragma unroll
        for (int j = 0; j < 4; ++j) {      // transpose: b64 along k for each of 4 n's
            u32x2 pb = { pk2(b0[j], b1[j]), pk2(b2[j], b3[j]) };
            *(u32x2*)&Bsh[bw0 + j * BK] = pb;
        }
        __syncthreads();
        if (kt + 1 < NKITER) {             // prefetch next K-tile (overlaps with MFMA below)
            a0 = *(const f32x4*)(ap0);      a1 = *(const f32x4*)(ap0 + 4);
            a2 = *(const f32x4*)(ap1);      a3 = *(const f32x4*)(ap1 + 4);
            b0 = *(const f32x4*)(bp);
            b1 = *(const f32x4*)(bp + NDIM);
            b2 = *(const f32x4*)(bp + 2 * NDIM);
            b3 = *(const f32x4*)(bp + 3 * NDIM);
            ap0 += BK; ap1 += BK; bp += (size_t)BK * NDIM;
        }
        // fragment loads (8 x ds_read_b128 per wave) + 16 MFMA
        bf16x8 af[4], bfr[4];
        #pragma unroll
        for (int i = 0; i < 4; ++i)
            af[i] = *(const bf16x8*)&Ash[(wm + i * 16 + fm) * ASTRIDE + fq * 8];
        #pragma unroll
        for (int j = 0; j < 4; ++j) {
            int n  = wn + j * 16 + fm;
            int su = fq ^ ((n >> 2) & 3);
            bfr[j] = *(const bf16x8*)&Bsh[n * BK + su * 8];
        }
        #pragma unroll
        for (int i = 0; i < 4; ++i)
            #pragma unroll
            for (int j = 0; j < 4; ++j)
                acc[i][j] = __builtin_amdgcn_mfma_f32_16x16x32_bf16(af[i], bfr[j], acc[i][j], 0, 0, 0);
    }

    // epilogue: C/D layout col=lane&15, row=(lane>>4)*4+reg  [m89-verified]
    const int r4 = fq * 4;
    #pragma unroll
    for (int i = 0; i < 4; ++i) {
        int mlbase = m0 + wm + i * 16 + r4;
        #pragma unroll
        for (int j = 0; j < 4; ++j) {
            int col = nb + wn + j * 16 + fm;
            #pragma unroll
            for (int rr = 0; rr < 4; ++rr) {
                int row = mlbase + rr;
                if (row < cnt)
                    Y[(size_t)(start + row) * NDIM + col] = acc[i][j][rr];
            }
        }
    }
}

extern "C" void kernel_launch(void* const* d_in, const int* in_sizes, int n_in,
                              void* d_out, int out_size, void* d_ws, size_t ws_size,
                              hipStream_t stream) {
    const float* X      = (const float*)d_in[0];
    const float* W      = (const float*)d_in[1];
    const int*   counts = (const int*)d_in[2];
    float*       Y      = (float*)d_out;
    dim3 grid(NDIM / BN, 2, NG);   // 13 x 2 x 64
    grouped_gemm<<<grid, 256, 0, stream>>>(X, W, counts, Y);
}